// Round 2
// baseline (602.850 us; speedup 1.0000x reference)
//
#include <hip/hip_runtime.h>

#define NNODES 50000
#define NEDGES 800000
#define NCHUNK (NEDGES / 64)    // 12500 chunks of 64 edges
#define NBLK 256
#define NWAVES (NBLK * 8)       // 2048 persistent waves

using short8 = __attribute__((ext_vector_type(8))) short;   // 8 bf16 = 4 VGPRs
using f32x4  = __attribute__((ext_vector_type(4))) float;   // MFMA accumulator

// fp32 -> bf16 round-to-nearest-even
__device__ __forceinline__ short f2b(float v) {
    unsigned u = __builtin_bit_cast(unsigned, v);
    u = (u + 0x7FFFu + ((u >> 16) & 1u)) >> 16;
    return (short)u;
}

// order-preserving float->uint for atomicMax; 0 = "empty" sentinel
__device__ __forceinline__ unsigned encf(float v) {
    unsigned u = __builtin_bit_cast(unsigned, v);
    return (u & 0x80000000u) ? ~u : (u | 0x80000000u);
}

__device__ __forceinline__ unsigned pk2(short a, short b) {
    return (unsigned)(unsigned short)a | ((unsigned)(unsigned short)b << 16);
}

// ---- prep: x (fp32) -> xb (bf16) ----
__global__ void prep_x(const float* __restrict__ x, short* __restrict__ xb) {
    int i = blockIdx.x * 256 + threadIdx.x;          // over float4 groups
    if (i < NNODES * 64 / 4) {
        float4 v = reinterpret_cast<const float4*>(x)[i];
        short4 o;
        o.x = f2b(v.x); o.y = f2b(v.y); o.z = f2b(v.z); o.w = f2b(v.w);
        reinterpret_cast<short4*>(xb)[i] = o;
    }
}

// ---- prep: pack W1/W2 to bf16 fragment order (lane=non-K idx, 8 contiguous K) ----
__global__ void prep_w(const float* __restrict__ W1, const float* __restrict__ W2,
                       short* __restrict__ wpk) {
    int i = blockIdx.x * 256 + threadIdx.x;
    if (i < 40960) {            // W1 [k<160][n<256]
        int k = i >> 8, n = i & 255;
        wpk[((n >> 4) * 20 + (k >> 3)) * 128 + (n & 15) * 8 + (k & 7)] = f2b(W1[i]);
    }
    if (i < 16384) {            // W2 [k<256][n<64]
        int k = i >> 6, n = i & 63;
        wpk[40960 + ((n >> 4) * 32 + (k >> 3)) * 128 + (n & 15) * 8 + (k & 7)] = f2b(W2[i]);
    }
}

// ---- main: persistent waves, 64 edges per wave-chunk, no hot-loop barriers ----
__global__ __launch_bounds__(512, 2)
void edgeconv_main(const short* __restrict__ xb, const int* __restrict__ ei,
                   const float* __restrict__ ea, const short* __restrict__ wpk,
                   const float* __restrict__ b1, const float* __restrict__ b2,
                   float* __restrict__ outbuf, unsigned* __restrict__ aggbuf)
{
    __shared__ short wbuf[57344];        // 112 KB: w1p[40960] + w2a[16384]
    __shared__ char  hbuf[8][64 * 80];   // 40 KB: per-wave h tile, 80-B row stride

    const int tid = threadIdx.x;
    // stage packed weights once per block (vectorized 16B copies)
    for (int i = tid; i < 7168; i += 512)
        reinterpret_cast<short8*>(wbuf)[i] = reinterpret_cast<const short8*>(wpk)[i];
    __syncthreads();                     // the only block-wide barrier

    const short* w1p = wbuf;
    const short* w2a = wbuf + 40960;
    const int wave = tid >> 6, lane = tid & 63;
    const int l16 = lane & 15, lg = lane >> 4;
    char* hw = hbuf[wave];
    const int gw = blockIdx.x * 8 + wave;

    for (int c = gw; c < NCHUNK; c += NWAVES) {
        const int ebase = c * 64;

        // ---- gather feats as GEMM1 B-fragments (col=edge=l16, k=lg*8..) ----
        int rn[4];
        short8 fx[4][5];
        #pragma unroll
        for (int nf = 0; nf < 4; ++nf) {
            int e = ebase + nf * 16 + l16;
            int r = ei[e], cc = ei[NEDGES + e];
            rn[nf] = r;
            fx[nf][0] = *reinterpret_cast<const short8*>(xb + r * 64 + lg * 8);
            fx[nf][1] = *reinterpret_cast<const short8*>(xb + r * 64 + 32 + lg * 8);
            fx[nf][2] = *reinterpret_cast<const short8*>(xb + cc * 64 + lg * 8);
            fx[nf][3] = *reinterpret_cast<const short8*>(xb + cc * 64 + 32 + lg * 8);
            const float4* eap = reinterpret_cast<const float4*>(ea + e * 32 + lg * 8);
            float4 va = eap[0], vb = eap[1];
            short8 f;
            f[0]=f2b(va.x); f[1]=f2b(va.y); f[2]=f2b(va.z); f[3]=f2b(va.w);
            f[4]=f2b(vb.x); f[5]=f2b(vb.y); f[6]=f2b(vb.z); f[7]=f2b(vb.w);
            fx[nf][4] = f;
        }

        f32x4 acc2[4][4] = {};   // [outcol-tile mt2][edge-tile nf]

        #pragma unroll
        for (int hp = 0; hp < 8; ++hp) {      // 8 half-phases of 32 H-cols
            // ---- GEMM1: h^T tile = W1^T @ feats^T ----
            f32x4 acc1[2][4] = {};
            #pragma unroll
            for (int kk = 0; kk < 5; ++kk) {
                #pragma unroll
                for (int mt = 0; mt < 2; ++mt) {
                    int nt = hp * 2 + mt;     // global 16-col H tile
                    short8 wf = *reinterpret_cast<const short8*>(
                        w1p + ((nt * 20 + kk * 4 + lg) * 16 + l16) * 8);
                    #pragma unroll
                    for (int nf = 0; nf < 4; ++nf)
                        acc1[mt][nf] = __builtin_amdgcn_mfma_f32_16x16x32_bf16(
                            wf, fx[nf][kk], acc1[mt][nf], 0, 0, 0);
                }
            }
            // ---- bias + ReLU + pack: 8-B writes, h[edge][hcol] k-contiguous ----
            #pragma unroll
            for (int mt = 0; mt < 2; ++mt) {
                float4 bb = *reinterpret_cast<const float4*>(b1 + hp * 32 + mt * 16 + lg * 4);
                #pragma unroll
                for (int nf = 0; nf < 4; ++nf) {
                    float v0 = fmaxf(acc1[mt][nf][0] + bb.x, 0.0f);
                    float v1 = fmaxf(acc1[mt][nf][1] + bb.y, 0.0f);
                    float v2 = fmaxf(acc1[mt][nf][2] + bb.z, 0.0f);
                    float v3 = fmaxf(acc1[mt][nf][3] + bb.w, 0.0f);
                    unsigned long long p =
                        (unsigned long long)pk2(f2b(v0), f2b(v1)) |
                        ((unsigned long long)pk2(f2b(v2), f2b(v3)) << 32);
                    *reinterpret_cast<unsigned long long*>(
                        hw + (nf * 16 + l16) * 80 + mt * 32 + lg * 8) = p;
                }
            }
            // ---- GEMM2 partial: out^T += W2^T @ h^T, K-chunk = 32 ----
            short8 hfr[4];
            #pragma unroll
            for (int nf = 0; nf < 4; ++nf)
                hfr[nf] = *reinterpret_cast<const short8*>(
                    hw + (nf * 16 + l16) * 80 + lg * 16);
            #pragma unroll
            for (int mt2 = 0; mt2 < 4; ++mt2) {
                short8 wf2 = *reinterpret_cast<const short8*>(
                    w2a + ((mt2 * 32 + hp * 4 + lg) * 16 + l16) * 8);
                #pragma unroll
                for (int nf = 0; nf < 4; ++nf)
                    acc2[mt2][nf] = __builtin_amdgcn_mfma_f32_16x16x32_bf16(
                        wf2, hfr[nf], acc2[mt2][nf], 0, 0, 0);
            }
        }

        // ---- epilogue: +b2, float4 out stores, atomicMax scatter ----
        #pragma unroll
        for (int mt2 = 0; mt2 < 4; ++mt2) {
            float4 bb = *reinterpret_cast<const float4*>(b2 + mt2 * 16 + lg * 4);
            #pragma unroll
            for (int nf = 0; nf < 4; ++nf) {
                int e = ebase + nf * 16 + l16;
                f32x4 v;
                v[0] = acc2[mt2][nf][0] + bb.x;
                v[1] = acc2[mt2][nf][1] + bb.y;
                v[2] = acc2[mt2][nf][2] + bb.z;
                v[3] = acc2[mt2][nf][3] + bb.w;
                __builtin_nontemporal_store(v,
                    reinterpret_cast<f32x4*>(outbuf + e * 64 + mt2 * 16 + lg * 4));
                unsigned* ap = aggbuf + rn[nf] * 64 + mt2 * 16 + lg * 4;
                atomicMax(ap + 0, encf(v[0]));
                atomicMax(ap + 1, encf(v[1]));
                atomicMax(ap + 2, encf(v[2]));
                atomicMax(ap + 3, encf(v[3]));
            }
        }
    }
}

// decode encoded agg in place: sentinel 0 -> 0.0f, else inverse order-map
__global__ void decode_agg(unsigned* __restrict__ agg)
{
    int i = blockIdx.x * 256 + threadIdx.x;
    if (i < NNODES * 64) {
        unsigned u = agg[i];
        float f;
        if (u == 0u)              f = 0.0f;
        else if (u & 0x80000000u) f = __builtin_bit_cast(float, u ^ 0x80000000u);
        else                      f = __builtin_bit_cast(float, ~u);
        reinterpret_cast<float*>(agg)[i] = f;
    }
}

extern "C" void kernel_launch(void* const* d_in, const int* in_sizes, int n_in,
                              void* d_out, int out_size, void* d_ws, size_t ws_size,
                              hipStream_t stream)
{
    const float* x  = (const float*)d_in[0];
    const int*   ei = (const int*)d_in[1];
    const float* ea = (const float*)d_in[2];
    const float* W1 = (const float*)d_in[3];
    const float* b1 = (const float*)d_in[4];
    const float* W2 = (const float*)d_in[5];
    const float* b2 = (const float*)d_in[6];
    float* outp = (float*)d_out;

    short* xb  = (short*)d_ws;                          // 6,400,000 B
    short* wpk = (short*)((char*)d_ws + 6400000);       //   114,688 B

    // agg region (N*64 u32) -> sentinel 0 ("empty")
    hipMemsetAsync(d_out, 0, (size_t)NNODES * 64 * sizeof(float), stream);
    prep_x<<<NNODES * 64 / 4 / 256, 256, 0, stream>>>(x, xb);
    prep_w<<<160, 256, 0, stream>>>(W1, W2, wpk);
    edgeconv_main<<<NBLK, 512, 0, stream>>>(
        xb, ei, ea, wpk, b1, b2,
        outp + (size_t)NNODES * 64,     // out section
        (unsigned*)d_out);              // agg section (encoded)
    decode_agg<<<(NNODES * 64 + 255) / 256, 256, 0, stream>>>((unsigned*)d_out);
}

// Round 3
// 582.916 us; speedup vs baseline: 1.0342x; 1.0342x over previous
//
#include <hip/hip_runtime.h>

#define NNODES 50000
#define NEDGES 800000

using short8 = __attribute__((ext_vector_type(8))) short;   // 8 bf16 = 4 VGPRs
using f32x4  = __attribute__((ext_vector_type(4))) float;   // MFMA accumulator

// fp32 -> bf16 round-to-nearest-even
__device__ __forceinline__ short f2b(float v) {
    unsigned u = __builtin_bit_cast(unsigned, v);
    u = (u + 0x7FFFu + ((u >> 16) & 1u)) >> 16;
    return (short)u;
}

// order-preserving float->uint for atomicMax; 0 = "empty" sentinel
__device__ __forceinline__ unsigned encf(float v) {
    unsigned u = __builtin_bit_cast(unsigned, v);
    return (u & 0x80000000u) ? ~u : (u | 0x80000000u);
}

__device__ __forceinline__ unsigned pk2(short a, short b) {
    return (unsigned)(unsigned short)a | ((unsigned)(unsigned short)b << 16);
}

// ---- prep: x (fp32) -> xb (bf16) ----
__global__ void prep_x(const float* __restrict__ x, short* __restrict__ xb) {
    int i = blockIdx.x * 256 + threadIdx.x;          // over float4 groups
    if (i < NNODES * 64 / 4) {
        float4 v = reinterpret_cast<const float4*>(x)[i];
        short4 o;
        o.x = f2b(v.x); o.y = f2b(v.y); o.z = f2b(v.z); o.w = f2b(v.w);
        reinterpret_cast<short4*>(xb)[i] = o;
    }
}

// ---- prep: pack W1/W2 to bf16 fragment order (lane=non-K idx, 8 contiguous K) ----
__global__ void prep_w(const float* __restrict__ W1, const float* __restrict__ W2,
                       short* __restrict__ wpk) {
    int i = blockIdx.x * 256 + threadIdx.x;
    if (i < 40960) {            // W1 [k<160][n<256]
        int k = i >> 8, n = i & 255;
        wpk[((n >> 4) * 20 + (k >> 3)) * 128 + (n & 15) * 8 + (k & 7)] = f2b(W1[i]);
    }
    if (i < 16384) {            // W2 [k<256][n<64]
        int k = i >> 6, n = i & 63;
        wpk[40960 + ((n >> 4) * 32 + (k >> 3)) * 128 + (n & 15) * 8 + (k & 7)] = f2b(W2[i]);
    }
}

// ---- main: 4 waves/block, 32 edges/wave, weights straight from L1/L2 ----
__global__ __launch_bounds__(256, 3)
void edgeconv_main(const short* __restrict__ xb, const int* __restrict__ ei,
                   const float* __restrict__ ea, const short* __restrict__ wpk,
                   const float* __restrict__ b1, const float* __restrict__ b2,
                   float* __restrict__ outbuf, unsigned* __restrict__ aggbuf)
{
    __shared__ char hbuf[4][32 * 80];   // 10,240 B: per-wave 32x32 h tile, 80-B stride

    const int tid  = threadIdx.x;
    const int wave = tid >> 6, lane = tid & 63;
    const int l16 = lane & 15, lg = lane >> 4;
    char* hw = hbuf[wave];
    const short* w2a = wpk + 40960;

    const int ebase = (blockIdx.x * 4 + wave) * 32;

    // ---- gather feats as GEMM1 B-fragments (col=edge=l16, k=lg*8..) ----
    int rn[2];
    short8 fx[2][5];
    #pragma unroll
    for (int nf = 0; nf < 2; ++nf) {
        int e = ebase + nf * 16 + l16;
        int r = ei[e], cc = ei[NEDGES + e];
        rn[nf] = r;
        fx[nf][0] = *reinterpret_cast<const short8*>(xb + r * 64 + lg * 8);
        fx[nf][1] = *reinterpret_cast<const short8*>(xb + r * 64 + 32 + lg * 8);
        fx[nf][2] = *reinterpret_cast<const short8*>(xb + cc * 64 + lg * 8);
        fx[nf][3] = *reinterpret_cast<const short8*>(xb + cc * 64 + 32 + lg * 8);
        const float4* eap = reinterpret_cast<const float4*>(ea + e * 32 + lg * 8);
        float4 va = eap[0], vb = eap[1];
        short8 f;
        f[0]=f2b(va.x); f[1]=f2b(va.y); f[2]=f2b(va.z); f[3]=f2b(va.w);
        f[4]=f2b(vb.x); f[5]=f2b(vb.y); f[6]=f2b(vb.z); f[7]=f2b(vb.w);
        fx[nf][4] = f;
    }

    f32x4 acc2[4][2] = {};   // [outcol-tile mt2][edge-tile nf]

    #pragma unroll 1
    for (int hp = 0; hp < 8; ++hp) {     // 8 phases of 32 H-cols
        // ---- GEMM1: h^T tile = W1^T @ feats^T (weight frags from global) ----
        f32x4 acc1[2][2] = {};
        #pragma unroll
        for (int kk = 0; kk < 5; ++kk) {
            #pragma unroll
            for (int mt = 0; mt < 2; ++mt) {
                int nt = hp * 2 + mt;
                short8 wf = *reinterpret_cast<const short8*>(
                    wpk + (nt * 20 + kk * 4 + lg) * 128 + l16 * 8);
                acc1[mt][0] = __builtin_amdgcn_mfma_f32_16x16x32_bf16(wf, fx[0][kk], acc1[mt][0], 0, 0, 0);
                acc1[mt][1] = __builtin_amdgcn_mfma_f32_16x16x32_bf16(wf, fx[1][kk], acc1[mt][1], 0, 0, 0);
            }
        }
        // ---- bias + ReLU + pack: 8-B LDS writes, h[edge][hcol] k-contiguous ----
        #pragma unroll
        for (int mt = 0; mt < 2; ++mt) {
            float4 bb = *reinterpret_cast<const float4*>(b1 + hp * 32 + mt * 16 + lg * 4);
            #pragma unroll
            for (int nf = 0; nf < 2; ++nf) {
                float v0 = fmaxf(acc1[mt][nf][0] + bb.x, 0.0f);
                float v1 = fmaxf(acc1[mt][nf][1] + bb.y, 0.0f);
                float v2 = fmaxf(acc1[mt][nf][2] + bb.z, 0.0f);
                float v3 = fmaxf(acc1[mt][nf][3] + bb.w, 0.0f);
                unsigned long long p =
                    (unsigned long long)pk2(f2b(v0), f2b(v1)) |
                    ((unsigned long long)pk2(f2b(v2), f2b(v3)) << 32);
                *reinterpret_cast<unsigned long long*>(
                    hw + (nf * 16 + l16) * 80 + mt * 32 + lg * 8) = p;
            }
        }
        // in-wave LDS RAW: drain DS writes, forbid compiler reordering
        asm volatile("s_waitcnt lgkmcnt(0)" ::: "memory");

        // ---- GEMM2 partial: out^T += W2^T @ h^T, K-chunk = 32 ----
        short8 hfr0 = *reinterpret_cast<const short8*>(hw + l16 * 80 + lg * 16);
        short8 hfr1 = *reinterpret_cast<const short8*>(hw + (16 + l16) * 80 + lg * 16);
        #pragma unroll
        for (int mt2 = 0; mt2 < 4; ++mt2) {
            short8 wf2 = *reinterpret_cast<const short8*>(
                w2a + (mt2 * 32 + hp * 4 + lg) * 128 + l16 * 8);
            acc2[mt2][0] = __builtin_amdgcn_mfma_f32_16x16x32_bf16(wf2, hfr0, acc2[mt2][0], 0, 0, 0);
            acc2[mt2][1] = __builtin_amdgcn_mfma_f32_16x16x32_bf16(wf2, hfr1, acc2[mt2][1], 0, 0, 0);
        }
        // keep next phase's LDS writes after this phase's reads (WAR, program order)
        asm volatile("" ::: "memory");
    }

    // ---- epilogue: +b2, float4 out stores, atomicMax scatter ----
    #pragma unroll
    for (int mt2 = 0; mt2 < 4; ++mt2) {
        float4 bb = *reinterpret_cast<const float4*>(b2 + mt2 * 16 + lg * 4);
        #pragma unroll
        for (int nf = 0; nf < 2; ++nf) {
            int e = ebase + nf * 16 + l16;
            f32x4 v;
            v[0] = acc2[mt2][nf][0] + bb.x;
            v[1] = acc2[mt2][nf][1] + bb.y;
            v[2] = acc2[mt2][nf][2] + bb.z;
            v[3] = acc2[mt2][nf][3] + bb.w;
            __builtin_nontemporal_store(v,
                reinterpret_cast<f32x4*>(outbuf + e * 64 + mt2 * 16 + lg * 4));
            unsigned* ap = aggbuf + rn[nf] * 64 + mt2 * 16 + lg * 4;
            atomicMax(ap + 0, encf(v[0]));
            atomicMax(ap + 1, encf(v[1]));
            atomicMax(ap + 2, encf(v[2]));
            atomicMax(ap + 3, encf(v[3]));
        }
    }
}

// decode encoded agg in place: sentinel 0 -> 0.0f, else inverse order-map
__global__ void decode_agg(unsigned* __restrict__ agg)
{
    int i = blockIdx.x * 256 + threadIdx.x;
    if (i < NNODES * 64) {
        unsigned u = agg[i];
        float f;
        if (u == 0u)              f = 0.0f;
        else if (u & 0x80000000u) f = __builtin_bit_cast(float, u ^ 0x80000000u);
        else                      f = __builtin_bit_cast(float, ~u);
        reinterpret_cast<float*>(agg)[i] = f;
    }
}

extern "C" void kernel_launch(void* const* d_in, const int* in_sizes, int n_in,
                              void* d_out, int out_size, void* d_ws, size_t ws_size,
                              hipStream_t stream)
{
    const float* x  = (const float*)d_in[0];
    const int*   ei = (const int*)d_in[1];
    const float* ea = (const float*)d_in[2];
    const float* W1 = (const float*)d_in[3];
    const float* b1 = (const float*)d_in[4];
    const float* W2 = (const float*)d_in[5];
    const float* b2 = (const float*)d_in[6];
    float* outp = (float*)d_out;

    short* xb  = (short*)d_ws;                          // 6,400,000 B
    short* wpk = (short*)((char*)d_ws + 6400000);       //   114,688 B

    // agg region (N*64 u32) -> sentinel 0 ("empty")
    hipMemsetAsync(d_out, 0, (size_t)NNODES * 64 * sizeof(float), stream);
    prep_x<<<NNODES * 64 / 4 / 256, 256, 0, stream>>>(x, xb);
    prep_w<<<160, 256, 0, stream>>>(W1, W2, wpk);
    edgeconv_main<<<NEDGES / 128, 256, 0, stream>>>(
        xb, ei, ea, wpk, b1, b2,
        outp + (size_t)NNODES * 64,     // out section
        (unsigned*)d_out);              // agg section (encoded)
    decode_agg<<<(NNODES * 64 + 255) / 256, 256, 0, stream>>>((unsigned*)d_out);
}